// Round 5
// baseline (354.208 us; speedup 1.0000x reference)
//
#include <hip/hip_runtime.h>
#include <hip/hip_bf16.h>

// SSD target assignment for MI355X.
// B=64 batches, N=64 gt objects, A=24564 anchors.
// Outputs (float32): classes [B,A] | locations [B,A,4] | masks [B,A]

#define NOBJ 64
#define OBJ_PER_BLOCK 16
#define TILE_ANC 1024

__device__ __forceinline__ float iou_corner(
    float ax0, float ay0, float ax1, float ay1, float aarea,
    float bx0, float by0, float bx1, float by1, float barea)
{
#pragma clang fp contract(off)
    float ltx = fmaxf(ax0, bx0);
    float lty = fmaxf(ay0, by0);
    float rbx = fminf(ax1, bx1);
    float rby = fminf(ay1, by1);
    float wx = fmaxf(rbx - ltx, 0.0f);
    float wy = fmaxf(rby - lty, 0.0f);
    float inter = wx * wy;
    float denom = (aarea + barea) - inter;   // keep un-fused (contract off)
    return inter / denom;
}

// Kernel 1: best anchor per object (argmax over A of iou[:, n], first-max tie-break).
// grid = (N/OBJ_PER_BLOCK, B), block = 256 = 16 objects x 16 scanner lanes.
__global__ __launch_bounds__(256) void k_best_anchor(
    const float4* __restrict__ gt_boxes,      // [B,N] corner boxes as float4
    const float4* __restrict__ center_anchor, // [A] cx,cy,w,h
    int* __restrict__ obj_idx,                // [B,N] out
    int A, int N)
{
#pragma clang fp contract(off)
    __shared__ float4 anc[TILE_ANC];          // 16 KB
    const int b   = blockIdx.y;
    const int o0  = blockIdx.x * OBJ_PER_BLOCK;
    const int tid = threadIdx.x;
    const int o   = tid >> 4;                 // 0..15 object within block
    const int t   = tid & 15;                 // scanner lane within object
    const int n   = o0 + o;

    const float4 box = gt_boxes[b * N + n];
    const float bx0 = box.x, by0 = box.y, bx1 = box.z, by1 = box.w;
    const float barea = (bx1 - bx0) * (by1 - by0);

    float best_v = -1.0f;
    int   best_i = 0;

    for (int base = 0; base < A; base += TILE_ANC) {
        const int tile_n = min(TILE_ANC, A - base);
        __syncthreads();
        for (int j = tid; j < tile_n; j += 256)
            anc[j] = center_anchor[base + j];
        __syncthreads();
        for (int j = t; j < tile_n; j += 16) {
            float4 ca = anc[j];
            float hw = ca.z * 0.5f, hh = ca.w * 0.5f;   // w/2 exact
            float ax0 = ca.x - hw, ay0 = ca.y - hh;
            float ax1 = ca.x + hw, ay1 = ca.y + hh;
            float aarea = (ax1 - ax0) * (ay1 - ay0);    // ref computes from corners
            float v = iou_corner(ax0, ay0, ax1, ay1, aarea,
                                 bx0, by0, bx1, by1, barea);
            if (v > best_v) { best_v = v; best_i = base + j; }  // first-max per thread
        }
    }
    // reduce across the 16 scanner lanes (contiguous within a wave)
    for (int m = 1; m < 16; m <<= 1) {
        float ov = __shfl_xor(best_v, m, 16);
        int   oi = __shfl_xor(best_i, m, 16);
        if (ov > best_v || (ov == best_v && oi < best_i)) { best_v = ov; best_i = oi; }
    }
    if (t == 0) obj_idx[b * N + n] = best_i;
}

// Kernel 2: per-anchor match + encode + store.
// grid = (ceil(A/256), B), block = 256, one thread per anchor.
__global__ __launch_bounds__(256) void k_match(
    const float4* __restrict__ gt_boxes,      // [B,N]
    const int*    __restrict__ gt_labels,     // [B,N]
    const float4* __restrict__ center_anchor, // [A]
    const int*    __restrict__ obj_idx,       // [B,N]
    float* __restrict__ out,                  // f32: classes | locations | masks
    int A, int N, int BA)                     // BA = B*A
{
#pragma clang fp contract(off)
    __shared__ float4 sbox[NOBJ];
    __shared__ int    slab[NOBJ];
    __shared__ int    sidx[NOBJ];
    const int b   = blockIdx.y;
    const int tid = threadIdx.x;
    if (tid < N) {
        sbox[tid] = gt_boxes[b * N + tid];
        slab[tid] = gt_labels[b * N + tid];
        sidx[tid] = obj_idx[b * N + tid];
    }
    __syncthreads();

    const int a = blockIdx.x * blockDim.x + tid;
    if (a >= A) return;

    const float4 ca = center_anchor[a];
    const float hw = ca.z * 0.5f, hh = ca.w * 0.5f;
    const float ax0 = ca.x - hw, ay0 = ca.y - hh;
    const float ax1 = ca.x + hw, ay1 = ca.y + hh;
    const float aarea = (ax1 - ax0) * (ay1 - ay0);

    float best_v = -1.0f;
    int   best_n = 0;
    bool  pos    = false;

    for (int nn = 0; nn < NOBJ; ++nn) {
        float4 bx = sbox[nn];
        float barea = (bx.z - bx.x) * (bx.w - bx.y);
        float v = iou_corner(ax0, ay0, ax1, ay1, aarea,
                             bx.x, bx.y, bx.z, bx.w, barea);
        if (sidx[nn] == a) v = 1.0f;          // force-match
        pos = pos || (v >= 0.5f);
        if (v > best_v) { best_v = v; best_n = nn; }   // numpy first-max
    }

    const int cls = pos ? (slab[best_n] + 1) : 0;

    // encode(xy_to_cxcy(box), center_anchor) — op order mirrors the reference
    const float4 gb = sbox[best_n];
    const float gcx = (gb.x + gb.z) * 0.5f;   // (x0+x2)/2 exact
    const float gcy = (gb.y + gb.w) * 0.5f;
    const float gw  = gb.z - gb.x;
    const float gh  = gb.w - gb.y;
    const float l0 = (gcx - ca.x) / (ca.z / 10.0f);   // keep /10 as division
    const float l1 = (gcy - ca.y) / (ca.w / 10.0f);
    const float l2 = __logf(gw / ca.z) * 5.0f;
    const float l3 = __logf(gh / ca.w) * 5.0f;

    const int idx = b * A + a;
    out[idx] = (float)cls;                    // classes [0, BA)

    float4 loc = make_float4(l0, l1, l2, l3);
    reinterpret_cast<float4*>(out + (size_t)BA)[idx] = loc;  // locations [BA, 5BA), 16B-aligned

    out[(size_t)5 * BA + idx] = pos ? 1.0f : 0.0f;           // masks [5BA, 6BA)
}

extern "C" void kernel_launch(void* const* d_in, const int* in_sizes, int n_in,
                              void* d_out, int out_size, void* d_ws, size_t ws_size,
                              hipStream_t stream) {
    const float4* gt_boxes      = (const float4*)d_in[0];
    const int*    gt_labels     = (const int*)d_in[1];
    const float4* center_anchor = (const float4*)d_in[2];

    const int N  = NOBJ;
    const int BN = in_sizes[1];       // B*N
    const int B  = BN / N;
    const int A  = in_sizes[2] / 4;
    const int BA = B * A;

    float* out = (float*)d_out;
    int* obj_idx = (int*)d_ws;        // B*N ints = 16 KB

    dim3 g1((N + OBJ_PER_BLOCK - 1) / OBJ_PER_BLOCK, B);
    k_best_anchor<<<g1, 256, 0, stream>>>(gt_boxes, center_anchor, obj_idx, A, N);

    dim3 g2((A + 255) / 256, B);
    k_match<<<g2, 256, 0, stream>>>(gt_boxes, gt_labels, center_anchor, obj_idx,
                                    out, A, N, BA);
}

// Round 6
// 228.462 us; speedup vs baseline: 1.5504x; 1.5504x over previous
//
#include <hip/hip_runtime.h>
#include <hip/hip_bf16.h>

// SSD target assignment for MI355X.
// B=64 batches, N=64 gt objects, A=24564 anchors.
// Outputs (float32): classes [B,A] | locations [B,A,4] | masks [B,A]
//
// ws layout: [B*N] u64 argmax keys: (iou_bits<<32)|~anchor_idx, combined via atomicMax.

#define NOBJ 64
#define TILE 512
#define SPLIT 2

__global__ void k_init(unsigned long long* __restrict__ ws, int n) {
    int i = blockIdx.x * blockDim.x + threadIdx.x;
    if (i < n) ws[i] = 0ull;
}

// Kernel 1: best anchor per object. One wave (64 lanes) per (object, anchor-half).
// grid = (N/4 * SPLIT, B) = (32, 64), block = 256 (4 waves = 4 objects).
__global__ __launch_bounds__(256) void k_best_anchor(
    const float4* __restrict__ gt_boxes,      // [B,N] corner boxes
    const float4* __restrict__ center_anchor, // [A] cx,cy,w,h
    unsigned long long* __restrict__ ws,      // [B,N] packed argmax keys
    int A, int N)
{
#pragma clang fp contract(off)
    __shared__ float4 sc[TILE];   // anchor corners (8 KB)
    __shared__ float  sa[TILE];   // anchor areas   (2 KB)
    const int b    = blockIdx.y;
    const int og   = blockIdx.x >> 1;        // object group 0..15
    const int half = blockIdx.x & 1;
    const int tid  = threadIdx.x;
    const int wv   = tid >> 6;               // wave in block = object in group
    const int lane = tid & 63;
    const int n    = og * 4 + wv;

    const int HALF = (A + SPLIT - 1) / SPLIT;
    const int beg  = half * HALF;
    const int end  = min(A, beg + HALF);

    const float4 box  = gt_boxes[b * N + n];
    const float barea = (box.z - box.x) * (box.w - box.y);

    float best_v = -1.0f;
    int   best_i = 0;

    for (int base = beg; base < end; base += TILE) {
        const int tn = min(TILE, end - base);
        __syncthreads();
        for (int j = tid; j < tn; j += 256) {
            float4 ca = center_anchor[base + j];
            float hw = ca.z * 0.5f, hh = ca.w * 0.5f;
            float ax0 = ca.x - hw, ay0 = ca.y - hh;
            float ax1 = ca.x + hw, ay1 = ca.y + hh;
            sc[j] = make_float4(ax0, ay0, ax1, ay1);
            sa[j] = (ax1 - ax0) * (ay1 - ay0);     // ref computes area from corners
        }
        __syncthreads();
        for (int j = lane; j < tn; j += 64) {
            float4 c = sc[j];
            float aarea = sa[j];
            float ltx = fmaxf(c.x, box.x), lty = fmaxf(c.y, box.y);
            float rbx = fminf(c.z, box.z), rby = fminf(c.w, box.w);
            float wx = fmaxf(rbx - ltx, 0.0f), wy = fmaxf(rby - lty, 0.0f);
            float inter = wx * wy;
            float v = inter / ((aarea + barea) - inter);   // IEEE div, un-fused
            if (v > best_v) { best_v = v; best_i = base + j; }  // first-max (ascending j)
        }
    }
    // full-wave butterfly reduce; equal value -> smaller index (numpy first-max)
    for (int m = 1; m < 64; m <<= 1) {
        float ov = __shfl_xor(best_v, m);
        int   oi = __shfl_xor(best_i, m);
        if (ov > best_v || (ov == best_v && oi < best_i)) { best_v = ov; best_i = oi; }
    }
    if (lane == 0) {
        unsigned long long key =
            ((unsigned long long)__float_as_uint(best_v) << 32) |
            (unsigned long long)(unsigned)(~(unsigned)best_i);
        atomicMax(&ws[b * N + n], key);
    }
}

// Kernel 2: per-anchor match + encode + store. One thread per (b, anchor).
__global__ __launch_bounds__(256) void k_match(
    const float4* __restrict__ gt_boxes,      // [B,N]
    const int*    __restrict__ gt_labels,     // [B,N]
    const float4* __restrict__ center_anchor, // [A]
    const unsigned long long* __restrict__ ws,// [B,N] keys
    float* __restrict__ out,                  // f32: classes | locations | masks
    int A, int N, int BA)
{
#pragma clang fp contract(off)
    __shared__ float4 sbox[NOBJ];
    __shared__ float  sbar[NOBJ];
    __shared__ int    slab[NOBJ];
    __shared__ int    sidx[NOBJ];
    const int b   = blockIdx.y;
    const int tid = threadIdx.x;
    if (tid < NOBJ) {
        float4 bx = gt_boxes[b * N + tid];
        sbox[tid] = bx;
        sbar[tid] = (bx.z - bx.x) * (bx.w - bx.y);
        slab[tid] = gt_labels[b * N + tid];
        sidx[tid] = (int)(~(unsigned)(ws[b * N + tid] & 0xffffffffull));
    }
    __syncthreads();

    const int a = blockIdx.x * 256 + tid;
    if (a >= A) return;

    const float4 ca = center_anchor[a];
    const float hw = ca.z * 0.5f, hh = ca.w * 0.5f;
    const float ax0 = ca.x - hw, ay0 = ca.y - hh;
    const float ax1 = ca.x + hw, ay1 = ca.y + hh;
    const float aarea = (ax1 - ax0) * (ay1 - ay0);

    float best_v = -1.0f;
    int   best_n = 0;

#pragma unroll 8
    for (int nn = 0; nn < NOBJ; ++nn) {
        float4 bx = sbox[nn];
        float ltx = fmaxf(ax0, bx.x), lty = fmaxf(ay0, bx.y);
        float rbx = fminf(ax1, bx.z), rby = fminf(ay1, bx.w);
        float wx = fmaxf(rbx - ltx, 0.0f), wy = fmaxf(rby - lty, 0.0f);
        float inter = wx * wy;
        float v = inter / ((aarea + sbar[nn]) - inter);
        if (sidx[nn] == a) v = 1.0f;          // force-match
        if (v > best_v) { best_v = v; best_n = nn; }   // numpy first-max
    }
    const bool pos = (best_v >= 0.5f);        // any(row>=.5) == max(row)>=.5
    const int  cls = pos ? (slab[best_n] + 1) : 0;

    // encode(xy_to_cxcy(box), center_anchor) — op order mirrors the reference
    const float4 gb = sbox[best_n];
    const float gcx = (gb.x + gb.z) * 0.5f;
    const float gcy = (gb.y + gb.w) * 0.5f;
    const float gw  = gb.z - gb.x;
    const float gh  = gb.w - gb.y;
    const float l0 = (gcx - ca.x) / (ca.z / 10.0f);
    const float l1 = (gcy - ca.y) / (ca.w / 10.0f);
    const float l2 = __logf(gw / ca.z) * 5.0f;
    const float l3 = __logf(gh / ca.w) * 5.0f;

    const int idx = b * A + a;
    out[idx] = (float)cls;                                   // classes
    reinterpret_cast<float4*>(out + (size_t)BA)[idx] =
        make_float4(l0, l1, l2, l3);                         // locations
    out[(size_t)5 * BA + idx] = pos ? 1.0f : 0.0f;           // masks
}

extern "C" void kernel_launch(void* const* d_in, const int* in_sizes, int n_in,
                              void* d_out, int out_size, void* d_ws, size_t ws_size,
                              hipStream_t stream) {
    const float4* gt_boxes      = (const float4*)d_in[0];
    const int*    gt_labels     = (const int*)d_in[1];
    const float4* center_anchor = (const float4*)d_in[2];

    const int N  = NOBJ;
    const int BN = in_sizes[1];       // B*N
    const int B  = BN / N;
    const int A  = in_sizes[2] / 4;
    const int BA = B * A;

    float* out = (float*)d_out;
    unsigned long long* ws = (unsigned long long*)d_ws;   // B*N u64 = 32 KB

    k_init<<<(BN + 255) / 256, 256, 0, stream>>>(ws, BN);

    dim3 g1((N / 4) * SPLIT, B);      // (32, 64)
    k_best_anchor<<<g1, 256, 0, stream>>>(gt_boxes, center_anchor, ws, A, N);

    dim3 g2((A + 255) / 256, B);      // (96, 64)
    k_match<<<g2, 256, 0, stream>>>(gt_boxes, gt_labels, center_anchor, ws,
                                    out, A, N, BA);
}

// Round 8
// 224.833 us; speedup vs baseline: 1.5754x; 1.0161x over previous
//
#include <hip/hip_runtime.h>
#include <hip/hip_bf16.h>

// SSD target assignment for MI355X.
// B=64 batches, N=64 gt objects, A=24564 anchors.
// Outputs (float32): classes [B,A] | locations [B,A,4] | masks [B,A]
//
// ws layout: [0,BN) u64 argmax keys ((iou_bits<<32)|~anchor_idx, atomicMax-combined),
//            then [BN) f32 per-object box areas.

#define NOBJ 64
#define SPLITK 4

// k0: zero keys + precompute per-object areas (every launch; ws is re-poisoned).
__global__ void k_init(const float4* __restrict__ gt_boxes,
                       unsigned long long* __restrict__ keys,
                       float* __restrict__ areas, int BN) {
#pragma clang fp contract(off)
    int i = blockIdx.x * blockDim.x + threadIdx.x;
    if (i < BN) {
        keys[i] = 0ull;
        float4 bx = gt_boxes[i];
        areas[i] = (bx.z - bx.x) * (bx.w - bx.y);
    }
}

// Kernel 1: best anchor per object. Barrier-free, LDS-free.
// Each wave: 2 objects x 1/SPLITK of the anchor range, anchors streamed from
// global (L2-resident, 393 KB). grid = (N/2*SPLITK/4, B) = (32, 64), block 256.
__global__ __launch_bounds__(256) void k_best_anchor(
    const float4* __restrict__ gt_boxes,      // [B,N] corner boxes
    const float4* __restrict__ center_anchor, // [A] cx,cy,w,h
    unsigned long long* __restrict__ keys,    // [B,N]
    int A, int N)
{
#pragma clang fp contract(off)
    const int b    = blockIdx.y;
    const int wv   = threadIdx.x >> 6;
    const int lane = threadIdx.x & 63;
    const int job  = blockIdx.x * 4 + wv;     // [0, N/2*SPLITK)
    const int pair = job >> 2;                // [0, N/2)
    const int spl  = job & (SPLITK - 1);
    const int n0   = pair * 2, n1 = n0 + 1;

    const int Q   = (A + SPLITK - 1) / SPLITK;
    const int beg = spl * Q;
    const int end = min(A, beg + Q);

    const float4 B0 = gt_boxes[b * N + n0];
    const float4 B1 = gt_boxes[b * N + n1];
    const float ar0 = (B0.z - B0.x) * (B0.w - B0.y);
    const float ar1 = (B1.z - B1.x) * (B1.w - B1.y);

    float bv0 = -1.0f, bv1 = -1.0f;
    int   bi0 = 0,     bi1 = 0;

    for (int j = beg + lane; j < end; j += 64) {
        float4 ca = center_anchor[j];
        float hw = ca.z * 0.5f, hh = ca.w * 0.5f;
        float ax0 = ca.x - hw, ay0 = ca.y - hh;
        float ax1 = ca.x + hw, ay1 = ca.y + hh;
        float aarea = (ax1 - ax0) * (ay1 - ay0);   // ref: area from corners

        // IoU vs object 0
        {
            float ltx = fmaxf(ax0, B0.x), lty = fmaxf(ay0, B0.y);
            float rbx = fminf(ax1, B0.z), rby = fminf(ay1, B0.w);
            float wx = fmaxf(rbx - ltx, 0.0f), wy = fmaxf(rby - lty, 0.0f);
            float inter = wx * wy;
            float v = inter / ((aarea + ar0) - inter);   // IEEE div, un-fused
            if (v > bv0) { bv0 = v; bi0 = j; }           // first-max (ascending j)
        }
        // IoU vs object 1
        {
            float ltx = fmaxf(ax0, B1.x), lty = fmaxf(ay0, B1.y);
            float rbx = fminf(ax1, B1.z), rby = fminf(ay1, B1.w);
            float wx = fmaxf(rbx - ltx, 0.0f), wy = fmaxf(rby - lty, 0.0f);
            float inter = wx * wy;
            float v = inter / ((aarea + ar1) - inter);
            if (v > bv1) { bv1 = v; bi1 = j; }
        }
    }
    // full-wave butterfly; equal value -> smaller index (numpy first-max)
    for (int m = 1; m < 64; m <<= 1) {
        float ov0 = __shfl_xor(bv0, m); int oi0 = __shfl_xor(bi0, m);
        float ov1 = __shfl_xor(bv1, m); int oi1 = __shfl_xor(bi1, m);
        if (ov0 > bv0 || (ov0 == bv0 && oi0 < bi0)) { bv0 = ov0; bi0 = oi0; }
        if (ov1 > bv1 || (ov1 == bv1 && oi1 < bi1)) { bv1 = ov1; bi1 = oi1; }
    }
    if (lane == 0) {
        unsigned long long k0 =
            ((unsigned long long)__float_as_uint(bv0) << 32) |
            (unsigned long long)(unsigned)(~(unsigned)bi0);
        unsigned long long k1 =
            ((unsigned long long)__float_as_uint(bv1) << 32) |
            (unsigned long long)(unsigned)(~(unsigned)bi1);
        atomicMax(&keys[b * N + n0], k0);
        atomicMax(&keys[b * N + n1], k1);
    }
}

// Kernel 2: per-anchor match + encode + store. One thread per (b, anchor).
// Inner loop reads box/area/forced-idx at wave-uniform addresses -> scalar loads.
__global__ __launch_bounds__(256) void k_match(
    const float4* __restrict__ gt_boxes,      // [B,N]
    const int*    __restrict__ gt_labels,     // [B,N]
    const float4* __restrict__ center_anchor, // [A]
    const unsigned long long* __restrict__ keys, // [B,N]
    const float*  __restrict__ areas,         // [B,N]
    float* __restrict__ out,                  // f32: classes | locations | masks
    int A, int N, int BA)
{
#pragma clang fp contract(off)
    __shared__ float4 sbox[NOBJ];   // epilogue gather only
    __shared__ int    slab[NOBJ];
    const int b   = blockIdx.y;
    const int tid = threadIdx.x;
    const int bN  = b * N;
    if (tid < NOBJ) {
        sbox[tid] = gt_boxes[bN + tid];
        slab[tid] = gt_labels[bN + tid];
    }
    __syncthreads();

    const int a = blockIdx.x * 256 + tid;
    if (a >= A) return;

    const float4 ca = center_anchor[a];
    const float hw = ca.z * 0.5f, hh = ca.w * 0.5f;
    const float ax0 = ca.x - hw, ay0 = ca.y - hh;
    const float ax1 = ca.x + hw, ay1 = ca.y + hh;
    const float aarea = (ax1 - ax0) * (ay1 - ay0);

    float best_v = -1.0f;
    int   best_n = 0;

#pragma unroll 8
    for (int nn = 0; nn < NOBJ; ++nn) {
        const float4 bx  = gt_boxes[bN + nn];                     // uniform -> s_load
        const float  bar = areas[bN + nn];                        // uniform -> s_load
        const int    fid = (int)(~(unsigned)(keys[bN + nn] & 0xffffffffull)); // uniform
        float ltx = fmaxf(ax0, bx.x), lty = fmaxf(ay0, bx.y);
        float rbx = fminf(ax1, bx.z), rby = fminf(ay1, bx.w);
        float wx = fmaxf(rbx - ltx, 0.0f), wy = fmaxf(rby - lty, 0.0f);
        float inter = wx * wy;
        float v = inter / ((aarea + bar) - inter);
        if (fid == a) v = 1.0f;                   // force-match
        if (v > best_v) { best_v = v; best_n = nn; }   // numpy first-max
    }
    const bool pos = (best_v >= 0.5f);            // any(row>=.5) == max(row)>=.5
    const int  cls = pos ? (slab[best_n] + 1) : 0;

    // encode(xy_to_cxcy(box), center_anchor) — op order mirrors the reference
    const float4 gb = sbox[best_n];
    const float gcx = (gb.x + gb.z) * 0.5f;
    const float gcy = (gb.y + gb.w) * 0.5f;
    const float gw  = gb.z - gb.x;
    const float gh  = gb.w - gb.y;
    const float l0 = (gcx - ca.x) / (ca.z / 10.0f);
    const float l1 = (gcy - ca.y) / (ca.w / 10.0f);
    const float l2 = __logf(gw / ca.z) * 5.0f;
    const float l3 = __logf(gh / ca.w) * 5.0f;

    const int idx = b * A + a;
    out[idx] = (float)cls;                                   // classes
    reinterpret_cast<float4*>(out + (size_t)BA)[idx] =
        make_float4(l0, l1, l2, l3);                         // locations
    out[(size_t)5 * BA + idx] = pos ? 1.0f : 0.0f;           // masks
}

extern "C" void kernel_launch(void* const* d_in, const int* in_sizes, int n_in,
                              void* d_out, int out_size, void* d_ws, size_t ws_size,
                              hipStream_t stream) {
    const float4* gt_boxes      = (const float4*)d_in[0];
    const int*    gt_labels     = (const int*)d_in[1];
    const float4* center_anchor = (const float4*)d_in[2];

    const int N  = NOBJ;
    const int BN = in_sizes[1];       // B*N
    const int B  = BN / N;
    const int A  = in_sizes[2] / 4;
    const int BA = B * A;

    float* out = (float*)d_out;
    unsigned long long* keys = (unsigned long long*)d_ws;           // 32 KB
    float* areas = (float*)((char*)d_ws + (size_t)BN * 8);          // 16 KB

    k_init<<<(BN + 255) / 256, 256, 0, stream>>>(gt_boxes, keys, areas, BN);

    dim3 g1((N / 2) * SPLITK / 4, B); // (32, 64)
    k_best_anchor<<<g1, 256, 0, stream>>>(gt_boxes, center_anchor, keys, A, N);

    dim3 g2((A + 255) / 256, B);      // (96, 64)
    k_match<<<g2, 256, 0, stream>>>(gt_boxes, gt_labels, center_anchor, keys,
                                    areas, out, A, N, BA);
}

// Round 10
// 193.676 us; speedup vs baseline: 1.8289x; 1.1609x over previous
//
#include <hip/hip_runtime.h>
#include <hip/hip_bf16.h>

// SSD target assignment for MI355X.
// B=64, N=64 objects, A=24564 anchors. Outputs f32: classes|locations|masks.
//
// Fast path (ws >= ~18.9MB): compute the B*N*A IoU matrix ONCE.
//   k_init_fast : zero per-object keys, gt areas, forced-map = INF
//   k_iou       : per (b,anchor-vec4) thread: 64 IoUs -> per-anchor best (pbest)
//                 + per-object column argmax via u64-key wave butterfly + atomicMax
//   k_forced    : scatter obj argmax -> forced[b,a] = min object idx (atomicMin)
//   k_final     : div-free: apply force-match, threshold, encode, store
// Fallback (small ws): round-8 proven two-pass kernels.

#define NOBJ 64
#define VEC 4
#define FINF 0x7FFFFFFF

// ============================ fast path ============================

__global__ void k_init_fast(const float4* __restrict__ gt_boxes,
                            unsigned long long* __restrict__ keys,
                            float* __restrict__ gareas,
                            int* __restrict__ forced,
                            int BN, int BA) {
#pragma clang fp contract(off)
    int i = blockIdx.x * blockDim.x + threadIdx.x;
    if (i < BN) {
        keys[i] = 0ull;
        float4 bx = gt_boxes[i];
        gareas[i] = (bx.z - bx.x) * (bx.w - bx.y);
    }
    if (i < BA) forced[i] = FINF;
}

// grid = (ceil(A/(4*64*VEC)), B), block 256 (4 waves; each wave owns 256 anchors)
__global__ __launch_bounds__(256) void k_iou(
    const float4* __restrict__ gt_boxes,      // [B,N]
    const float4* __restrict__ center_anchor, // [A]
    const float*  __restrict__ gareas,        // [B,N]
    unsigned long long* __restrict__ keys,    // [B,N] per-object argmax keys
    unsigned long long* __restrict__ pbest,   // [B,A] per-anchor (iou_bits<<32)|n
    int A, int N)
{
#pragma clang fp contract(off)
    const int b     = blockIdx.y;
    const int wv    = threadIdx.x >> 6;
    const int lane  = threadIdx.x & 63;
    const int wbase = (blockIdx.x * 4 + wv) * (64 * VEC);
    const int bN    = b * N;

    // preload VEC anchors/lane; corners+area computed once (amortized over 64 objects)
    float ax0[VEC], ay0[VEC], ax1[VEC], ay1[VEC], aar[VEC];
    int   aidx[VEC];
    bool  val[VEC];
#pragma unroll
    for (int v = 0; v < VEC; ++v) {
        int a   = wbase + v * 64 + lane;
        val[v]  = (a < A);
        int ac  = val[v] ? a : (A - 1);
        float4 ca = center_anchor[ac];
        float hw = ca.z * 0.5f, hh = ca.w * 0.5f;
        ax0[v] = ca.x - hw; ay0[v] = ca.y - hh;
        ax1[v] = ca.x + hw; ay1[v] = ca.y + hh;
        aar[v] = (ax1[v] - ax0[v]) * (ay1[v] - ay0[v]);   // ref: area from corners
        aidx[v] = a;
    }
    float bv[VEC]; int bn[VEC];
#pragma unroll
    for (int v = 0; v < VEC; ++v) { bv[v] = -1.0f; bn[v] = 0; }

    for (int n = 0; n < NOBJ; ++n) {
        const float4 bx  = gt_boxes[bN + n];   // wave-uniform -> scalar load
        const float  bar = gareas[bN + n];     // wave-uniform
        float mv = -1.0f; int ma = 0;
#pragma unroll
        for (int v = 0; v < VEC; ++v) {
            float ltx = fmaxf(ax0[v], bx.x), lty = fmaxf(ay0[v], bx.y);
            float rbx = fminf(ax1[v], bx.z), rby = fminf(ay1[v], bx.w);
            float wx = fmaxf(rbx - ltx, 0.0f), wy = fmaxf(rby - lty, 0.0f);
            float inter = wx * wy;
            float iou = inter / ((aar[v] + bar) - inter);  // IEEE div, un-fused
            if (val[v]) {
                if (iou > bv[v]) { bv[v] = iou; bn[v] = n; }      // first-max over n
                if (iou > mv)    { mv = iou;    ma = aidx[v]; }   // first-max over a (asc v)
            }
        }
        // pack (value, ~index): u64 max == (bigger value, then smaller anchor idx)
        unsigned long long mk = (mv >= 0.0f)
            ? (((unsigned long long)__float_as_uint(mv) << 32) |
               (unsigned long long)(unsigned)(~(unsigned)ma))
            : 0ull;
        for (int m = 1; m < 64; m <<= 1) {
            unsigned long long ok = __shfl_xor(mk, m);
            if (ok > mk) mk = ok;
        }
        if (lane == 0 && mk != 0ull) atomicMax(&keys[bN + n], mk);
    }
    const long long base = (long long)b * A;
#pragma unroll
    for (int v = 0; v < VEC; ++v) {
        if (val[v]) {
            pbest[base + aidx[v]] =
                ((unsigned long long)__float_as_uint(bv[v]) << 32) |
                (unsigned long long)(unsigned)bn[v];
        }
    }
}

__global__ void k_forced(const unsigned long long* __restrict__ keys,
                         int* __restrict__ forced, int A, int N, int BN) {
    int i = blockIdx.x * blockDim.x + threadIdx.x;
    if (i < BN) {
        int b = i >> 6, n = i & 63;            // N == 64
        int aidx = (int)(~(unsigned)(keys[i] & 0xffffffffull));
        atomicMin(&forced[(long long)b * A + aidx], n);
    }
}

// grid = (ceil(A/256), B), block 256. No divisions here.
__global__ __launch_bounds__(256) void k_final(
    const float4* __restrict__ gt_boxes,      // [B,N]
    const int*    __restrict__ gt_labels,     // [B,N]
    const float4* __restrict__ center_anchor, // [A]
    const unsigned long long* __restrict__ pbest, // [B,A]
    const int*    __restrict__ forced,        // [B,A]
    float* __restrict__ out, int A, int N, int BA)
{
#pragma clang fp contract(off)
    __shared__ float4 sbox[NOBJ];
    __shared__ int    slab[NOBJ];
    const int b = blockIdx.y, tid = threadIdx.x, bN = b * N;
    if (tid < NOBJ) { sbox[tid] = gt_boxes[bN + tid]; slab[tid] = gt_labels[bN + tid]; }
    __syncthreads();

    const int a = blockIdx.x * 256 + tid;
    if (a >= A) return;
    const long long ia = (long long)b * A + a;

    const unsigned long long pb = pbest[ia];
    const float bv  = __uint_as_float((unsigned)(pb >> 32));
    const int   bn  = (int)(pb & 0xffffffffull);
    const int   fid = forced[ia];

    bool pos; int best;
    if (fid != FINF) {
        // row has forced 1.0 at fid (min forced n). Unforced max bv<=1.0.
        pos  = true;
        best = (bv == 1.0f && bn < fid) ? bn : fid;   // numpy first-max on modified row
    } else {
        pos  = (bv >= 0.5f);
        best = bn;
    }
    const int cls = pos ? (slab[best] + 1) : 0;

    const float4 ca = center_anchor[a];
    const float4 gb = sbox[best];
    const float gcx = (gb.x + gb.z) * 0.5f;
    const float gcy = (gb.y + gb.w) * 0.5f;
    const float gw  = gb.z - gb.x;
    const float gh  = gb.w - gb.y;
    const float l0 = (gcx - ca.x) / (ca.z / 10.0f);
    const float l1 = (gcy - ca.y) / (ca.w / 10.0f);
    const float l2 = __logf(gw / ca.z) * 5.0f;
    const float l3 = __logf(gh / ca.w) * 5.0f;

    const int idx = b * A + a;
    out[idx] = (float)cls;
    reinterpret_cast<float4*>(out + (size_t)BA)[idx] = make_float4(l0, l1, l2, l3);
    out[(size_t)5 * BA + idx] = pos ? 1.0f : 0.0f;
}

// ============================ fallback path (round-8, proven) ============================

#define SPLITK 4

__global__ void k_init_fb(const float4* __restrict__ gt_boxes,
                          unsigned long long* __restrict__ keys,
                          float* __restrict__ areas, int BN) {
#pragma clang fp contract(off)
    int i = blockIdx.x * blockDim.x + threadIdx.x;
    if (i < BN) {
        keys[i] = 0ull;
        float4 bx = gt_boxes[i];
        areas[i] = (bx.z - bx.x) * (bx.w - bx.y);
    }
}

__global__ __launch_bounds__(256) void k_best_anchor(
    const float4* __restrict__ gt_boxes,
    const float4* __restrict__ center_anchor,
    unsigned long long* __restrict__ keys, int A, int N)
{
#pragma clang fp contract(off)
    const int b    = blockIdx.y;
    const int wv   = threadIdx.x >> 6;
    const int lane = threadIdx.x & 63;
    const int job  = blockIdx.x * 4 + wv;
    const int pair = job >> 2;
    const int spl  = job & (SPLITK - 1);
    const int n0   = pair * 2, n1 = n0 + 1;

    const int Q   = (A + SPLITK - 1) / SPLITK;
    const int beg = spl * Q;
    const int end = min(A, beg + Q);

    const float4 B0 = gt_boxes[b * N + n0];
    const float4 B1 = gt_boxes[b * N + n1];
    const float ar0 = (B0.z - B0.x) * (B0.w - B0.y);
    const float ar1 = (B1.z - B1.x) * (B1.w - B1.y);

    float bv0 = -1.0f, bv1 = -1.0f;
    int   bi0 = 0,     bi1 = 0;

    for (int j = beg + lane; j < end; j += 64) {
        float4 ca = center_anchor[j];
        float hw = ca.z * 0.5f, hh = ca.w * 0.5f;
        float ax0 = ca.x - hw, ay0 = ca.y - hh;
        float ax1 = ca.x + hw, ay1 = ca.y + hh;
        float aarea = (ax1 - ax0) * (ay1 - ay0);
        {
            float ltx = fmaxf(ax0, B0.x), lty = fmaxf(ay0, B0.y);
            float rbx = fminf(ax1, B0.z), rby = fminf(ay1, B0.w);
            float wx = fmaxf(rbx - ltx, 0.0f), wy = fmaxf(rby - lty, 0.0f);
            float inter = wx * wy;
            float v = inter / ((aarea + ar0) - inter);
            if (v > bv0) { bv0 = v; bi0 = j; }
        }
        {
            float ltx = fmaxf(ax0, B1.x), lty = fmaxf(ay0, B1.y);
            float rbx = fminf(ax1, B1.z), rby = fminf(ay1, B1.w);
            float wx = fmaxf(rbx - ltx, 0.0f), wy = fmaxf(rby - lty, 0.0f);
            float inter = wx * wy;
            float v = inter / ((aarea + ar1) - inter);
            if (v > bv1) { bv1 = v; bi1 = j; }
        }
    }
    for (int m = 1; m < 64; m <<= 1) {
        float ov0 = __shfl_xor(bv0, m); int oi0 = __shfl_xor(bi0, m);
        float ov1 = __shfl_xor(bv1, m); int oi1 = __shfl_xor(bi1, m);
        if (ov0 > bv0 || (ov0 == bv0 && oi0 < bi0)) { bv0 = ov0; bi0 = oi0; }
        if (ov1 > bv1 || (ov1 == bv1 && oi1 < bi1)) { bv1 = ov1; bi1 = oi1; }
    }
    if (lane == 0) {
        unsigned long long k0 =
            ((unsigned long long)__float_as_uint(bv0) << 32) |
            (unsigned long long)(unsigned)(~(unsigned)bi0);
        unsigned long long k1 =
            ((unsigned long long)__float_as_uint(bv1) << 32) |
            (unsigned long long)(unsigned)(~(unsigned)bi1);
        atomicMax(&keys[b * N + n0], k0);
        atomicMax(&keys[b * N + n1], k1);
    }
}

__global__ __launch_bounds__(256) void k_match(
    const float4* __restrict__ gt_boxes,
    const int*    __restrict__ gt_labels,
    const float4* __restrict__ center_anchor,
    const unsigned long long* __restrict__ keys,
    const float*  __restrict__ areas,
    float* __restrict__ out, int A, int N, int BA)
{
#pragma clang fp contract(off)
    __shared__ float4 sbox[NOBJ];
    __shared__ int    slab[NOBJ];
    const int b = blockIdx.y, tid = threadIdx.x, bN = b * N;
    if (tid < NOBJ) { sbox[tid] = gt_boxes[bN + tid]; slab[tid] = gt_labels[bN + tid]; }
    __syncthreads();

    const int a = blockIdx.x * 256 + tid;
    if (a >= A) return;

    const float4 ca = center_anchor[a];
    const float hw = ca.z * 0.5f, hh = ca.w * 0.5f;
    const float ax0 = ca.x - hw, ay0 = ca.y - hh;
    const float ax1 = ca.x + hw, ay1 = ca.y + hh;
    const float aarea = (ax1 - ax0) * (ay1 - ay0);

    float best_v = -1.0f;
    int   best_n = 0;

#pragma unroll 8
    for (int nn = 0; nn < NOBJ; ++nn) {
        const float4 bx  = gt_boxes[bN + nn];
        const float  bar = areas[bN + nn];
        const int    fid = (int)(~(unsigned)(keys[bN + nn] & 0xffffffffull));
        float ltx = fmaxf(ax0, bx.x), lty = fmaxf(ay0, bx.y);
        float rbx = fminf(ax1, bx.z), rby = fminf(ay1, bx.w);
        float wx = fmaxf(rbx - ltx, 0.0f), wy = fmaxf(rby - lty, 0.0f);
        float inter = wx * wy;
        float v = inter / ((aarea + bar) - inter);
        if (fid == a) v = 1.0f;
        if (v > best_v) { best_v = v; best_n = nn; }
    }
    const bool pos = (best_v >= 0.5f);
    const int  cls = pos ? (slab[best_n] + 1) : 0;

    const float4 gb = sbox[best_n];
    const float gcx = (gb.x + gb.z) * 0.5f;
    const float gcy = (gb.y + gb.w) * 0.5f;
    const float gw  = gb.z - gb.x;
    const float gh  = gb.w - gb.y;
    const float l0 = (gcx - ca.x) / (ca.z / 10.0f);
    const float l1 = (gcy - ca.y) / (ca.w / 10.0f);
    const float l2 = __logf(gw / ca.z) * 5.0f;
    const float l3 = __logf(gh / ca.w) * 5.0f;

    const int idx = b * A + a;
    out[idx] = (float)cls;
    reinterpret_cast<float4*>(out + (size_t)BA)[idx] = make_float4(l0, l1, l2, l3);
    out[(size_t)5 * BA + idx] = pos ? 1.0f : 0.0f;
}

// ============================ launcher ============================

extern "C" void kernel_launch(void* const* d_in, const int* in_sizes, int n_in,
                              void* d_out, int out_size, void* d_ws, size_t ws_size,
                              hipStream_t stream) {
    const float4* gt_boxes      = (const float4*)d_in[0];
    const int*    gt_labels     = (const int*)d_in[1];
    const float4* center_anchor = (const float4*)d_in[2];

    const int N  = NOBJ;
    const int BN = in_sizes[1];       // B*N
    const int B  = BN / N;
    const int A  = in_sizes[2] / 4;
    const int BA = B * A;
    float* out = (float*)d_out;

    // ws layout (fast): keys u64[BN] | gareas f32[BN] | forced i32[BA] | pbest u64[BA]
    char* w = (char*)d_ws;
    unsigned long long* keys   = (unsigned long long*)w;
    float*              gareas = (float*)(w + (size_t)BN * 8);
    size_t off_forced = (size_t)BN * 8 + (size_t)BN * 4;
    off_forced = (off_forced + 7) & ~(size_t)7;
    int*                forced = (int*)(w + off_forced);
    size_t off_pbest = off_forced + (size_t)BA * 4;
    off_pbest = (off_pbest + 7) & ~(size_t)7;
    unsigned long long* pbest  = (unsigned long long*)(w + off_pbest);
    const size_t need = off_pbest + (size_t)BA * 8;

    if (ws_size >= need) {
        k_init_fast<<<(BA + 255) / 256, 256, 0, stream>>>(gt_boxes, keys, gareas,
                                                          forced, BN, BA);
        const int APB = 4 * 64 * VEC;                 // anchors per block = 1024
        dim3 g1((A + APB - 1) / APB, B);              // (24, 64)
        k_iou<<<g1, 256, 0, stream>>>(gt_boxes, center_anchor, gareas,
                                      keys, pbest, A, N);
        k_forced<<<(BN + 255) / 256, 256, 0, stream>>>(keys, forced, A, N, BN);
        dim3 g2((A + 255) / 256, B);
        k_final<<<g2, 256, 0, stream>>>(gt_boxes, gt_labels, center_anchor,
                                        pbest, forced, out, A, N, BA);
    } else {
        k_init_fb<<<(BN + 255) / 256, 256, 0, stream>>>(gt_boxes, keys, gareas, BN);
        dim3 g1((N / 2) * SPLITK / 4, B);
        k_best_anchor<<<g1, 256, 0, stream>>>(gt_boxes, center_anchor, keys, A, N);
        dim3 g2((A + 255) / 256, B);
        k_match<<<g2, 256, 0, stream>>>(gt_boxes, gt_labels, center_anchor, keys,
                                        gareas, out, A, N, BA);
    }
}